// Round 11
// baseline (231.816 us; speedup 1.0000x reference)
//
#include <hip/hip_runtime.h>
#include <stdint.h>

// Depthwise causal conv1d, channel-last. x:(B,L,D) f32, w:(K,1,D), b:(D), y:(B,L,D).
// y[n,l,d] = sum_k w[k,d]*x[n,l+k-3,d] + b[d], zero-padded left.
//
// R15 == R14 resubmitted (broker infra flake; never reached HW -- same as
// R7/R8/R10, and identical-source retries have always run fine).
//
// R14: R13 champion with ONE change: plain stores instead of
// __builtin_nontemporal_store. Theory: y (134 MB) FITS in the 256 MB
// Infinity Cache; NT stores forfeit it, forcing every write onto the HBM
// path inside the dispatch window -- the invariant write-drain floor that
// kept all five structural variants (R6/R9/R11/R12/R13) in the 72-87 us
// band regardless of occupancy/MLP/pattern. Plain stores let writes retire
// into L2/L3 and overlap/defer the HBM writeback. The harness fill can't
// exploit this (537 MB > L3); our kernel can.
//
// Structure (unchanged): stage 35 row-strips (32 rows + 3 halo) of a 1 KB
// channel strip into LDS via global_load_lds (width 16, fire-and-forget, no
// dest VGPRs -- unsinkable), one barrier, then each wave computes 8 rows
// with a register sliding window. 35 KB LDS -> 4 blocks/CU.

#define CB 4
#define CL 4096
#define CD 2048
#define STRIP 256               // floats per channel strip (1 KB per row-strip)
#define SF4 (STRIP / 4)         // 64 float4 per row-strip = one wave-load
#define ROWS 32                 // output rows per block
#define HALO 3
#define LROWS (ROWS + HALO)     // 35 staged rows
#define NSTRIP (CD / STRIP)     // 8
#define NCHUNK (CL / ROWS)      // 128

typedef float nfloat4 __attribute__((ext_vector_type(4)));

__global__ __launch_bounds__(256) void short_conv_kernel(
    const float* __restrict__ x,
    const float* __restrict__ w,
    const float* __restrict__ bias,
    float* __restrict__ y)
{
    __shared__ float lds[LROWS * STRIP];   // 35 KB -> 4 blocks/CU

    const int tid  = threadIdx.x;
    const int lane = tid & 63;
    const int wv   = tid >> 6;

    const int bid    = blockIdx.x;
    const int strip  = bid & (NSTRIP - 1);
    const int lchunk = (bid >> 3) & (NCHUNK - 1);
    const int b      = bid >> 10;

    const int l0 = lchunk * ROWS;
    const int c0 = strip * STRIP;

    const float* xs = x + (size_t)b * CL * CD + c0;   // strip base, row stride CD
    float*       ys = y + (size_t)b * CL * CD + c0;

    // Zero the 3 causal-halo rows for the first chunk (768 float4 = 192 threads).
    // Wave-uniform branch (waves 0-2 all true, wave 3 all false).
    if (l0 == 0 && tid < HALO * SF4) {
        ((float4*)lds)[tid] = make_float4(0.f, 0.f, 0.f, 0.f);
    }

    // ---- Stage LROWS row-strips: LDS row r <- global row (l0 - 3 + r). ----
    // One wave-instruction moves one full 1 KB row-strip (lane i -> base+16i).
    // Fire-and-forget: ~9 KB outstanding per wave, no destination VGPRs.
    for (int r = wv; r < LROWS; r += 4) {
        const int l = l0 - HALO + r;               // wave-uniform
        if (l >= 0) {
            const float* gsrc = xs + (size_t)l * CD + lane * 4;
            float* ldst = &lds[r * STRIP + lane * 4];
            __builtin_amdgcn_global_load_lds(
                (const __attribute__((address_space(1))) uint32_t*)gsrc,
                (__attribute__((address_space(3))) uint32_t*)ldst,
                16, 0, 0);
        }
    }

    // Per-lane weights/bias for columns c0 + lane*4 .. +3 (L2-resident, tiny).
    const float4 w0 = *(const float4*)(w + 0 * CD + c0 + lane * 4);
    const float4 w1 = *(const float4*)(w + 1 * CD + c0 + lane * 4);
    const float4 w2 = *(const float4*)(w + 2 * CD + c0 + lane * 4);
    const float4 w3 = *(const float4*)(w + 3 * CD + c0 + lane * 4);
    const float4 bv = *(const float4*)(bias + c0 + lane * 4);

    __syncthreads();   // drains vmcnt (load_lds) + lgkmcnt (halo zeros)

    // ---- Compute: wave wv owns output rows wv*8 .. wv*8+7. ----
    // Register sliding window: 11 ds_read_b128 per wave for 8 outputs.
    const int o0 = wv * 8;
    const float4* lrow = (const float4*)lds + lane;     // row stride SF4

    float4 xm3 = lrow[(o0 + 0) * SF4];
    float4 xm2 = lrow[(o0 + 1) * SF4];
    float4 xm1 = lrow[(o0 + 2) * SF4];

#pragma unroll
    for (int t = 0; t < 8; ++t) {
        const float4 a0 = lrow[(o0 + t + HALO) * SF4];

        nfloat4 r;
        r.x = fmaf(w0.x, xm3.x, fmaf(w1.x, xm2.x, fmaf(w2.x, xm1.x, fmaf(w3.x, a0.x, bv.x))));
        r.y = fmaf(w0.y, xm3.y, fmaf(w1.y, xm2.y, fmaf(w2.y, xm1.y, fmaf(w3.y, a0.y, bv.y))));
        r.z = fmaf(w0.z, xm3.z, fmaf(w1.z, xm2.z, fmaf(w2.z, xm1.z, fmaf(w3.z, a0.z, bv.z))));
        r.w = fmaf(w0.w, xm3.w, fmaf(w1.w, xm2.w, fmaf(w2.w, xm1.w, fmaf(w3.w, a0.w, bv.w))));

        const int l = l0 + o0 + t;
        // Plain store: writes allocate in L2/L3 (y fits in 256 MB MALL);
        // HBM writeback overlaps/defers instead of gating the dispatch.
        *(nfloat4*)(ys + (size_t)l * CD + lane * 4) = r;

        xm3 = xm2;
        xm2 = xm1;
        xm1 = a0;
    }
}

extern "C" void kernel_launch(void* const* d_in, const int* in_sizes, int n_in,
                              void* d_out, int out_size, void* d_ws, size_t ws_size,
                              hipStream_t stream) {
    const float* x = (const float*)d_in[0];
    const float* w = (const float*)d_in[1];
    const float* b = (const float*)d_in[2];
    float* y = (float*)d_out;

    const int grid = CB * NCHUNK * NSTRIP;   // 4 * 128 * 8 = 4096 blocks
    short_conv_kernel<<<grid, 256, 0, stream>>>(x, w, b, y);
}